// Round 2
// baseline (587.160 us; speedup 1.0000x reference)
//
#include <hip/hip_runtime.h>

typedef unsigned short ushort_t;
typedef __attribute__((ext_vector_type(8))) short bf16x8;
typedef __attribute__((ext_vector_type(4))) float f32x4;

#define LOG2E 1.44269504088896340736f

__device__ inline ushort_t f2bf(float f) {
    unsigned int u = __float_as_uint(f);
    unsigned int r = (u + 0x7FFFu + ((u >> 16) & 1u)) >> 16;
    return (ushort_t)r;
}

// ---------------- transpose + cast: W[K,N] f32 -> Wt[N,K] bf16 (1024x1024) ----
__global__ __launch_bounds__(256) void transpose_cast(const float* __restrict__ W,
                                                      ushort_t* __restrict__ Wt) {
    __shared__ float tile[32][33];
    const int bx = blockIdx.x & 31;   // n tile
    const int by = blockIdx.x >> 5;   // k tile
    const int n0 = bx * 32, k0 = by * 32;
    const int tx = threadIdx.x & 31, ty = threadIdx.x >> 5;  // ty 0..7
#pragma unroll
    for (int i = 0; i < 4; ++i) {
        int r = ty + i * 8;
        tile[r][tx] = W[(k0 + r) * 1024 + n0 + tx];
    }
    __syncthreads();
#pragma unroll
    for (int i = 0; i < 4; ++i) {
        int r = ty + i * 8;  // n offset
        Wt[(n0 + r) * 1024 + k0 + tx] = f2bf(tile[tx][r]);
    }
}

// ---------------- V transpose: Vp[pair][s][d=64] -> Vt[pair][d][s=2048] bf16 --
__global__ __launch_bounds__(256) void v_transpose(const ushort_t* __restrict__ Vp,
                                                   ushort_t* __restrict__ Vt) {
    __shared__ alignas(16) ushort_t tile[64][72];
    const int bid = blockIdx.x;
    const int pair = bid >> 5, st0 = (bid & 31) * 64;
    const ushort_t* src = Vp + (size_t)pair * 2048 * 64;
    ushort_t* dst = Vt + (size_t)pair * 64 * 2048;
    const int t = threadIdx.x;
    const int sl = t >> 2, d0 = (t & 3) * 16;
    *(bf16x8*)&tile[sl][d0] = *(const bf16x8*)&src[(size_t)(st0 + sl) * 64 + d0];
    *(bf16x8*)&tile[sl][d0 + 8] = *(const bf16x8*)&src[(size_t)(st0 + sl) * 64 + d0 + 8];
    __syncthreads();
    const int dl = t >> 2, s0 = (t & 3) * 16;
    bf16x8 a, b;
#pragma unroll
    for (int j = 0; j < 8; ++j) {
        a[j] = (short)tile[s0 + j][dl];
        b[j] = (short)tile[s0 + 8 + j][dl];
    }
    *(bf16x8*)&dst[(size_t)dl * 2048 + st0 + s0] = a;
    *(bf16x8*)&dst[(size_t)dl * 2048 + st0 + s0 + 8] = b;
}

// ---------------- GEMM: C[M=8192, N=1024] = A[M,1024] @ Wt[N,1024]^T + bias ---
// AF32: A operand is fp32 (converted to bf16 while staging); else bf16.
// OMODE 0: write bf16 split-heads [B,H,S,D] scaled; OMODE 1: write f32 [M,N].
template <int AF32, int OMODE>
__global__ __launch_bounds__(256) void gemm_bt(const void* __restrict__ Ap,
                                               const ushort_t* __restrict__ Bt,
                                               const float* __restrict__ bias,
                                               void* __restrict__ out, float scale) {
    __shared__ alignas(16) ushort_t As[128 * 72];
    __shared__ alignas(16) ushort_t Bs[128 * 72];
    const int t = threadIdx.x;
    const int lane = t & 63, w = t >> 6;
    const int q = lane & 15, g = lane >> 4;
    const int wr = w >> 1, wc = w & 1;
    const int bm = blockIdx.x & 63, bn = blockIdx.x >> 6;
    const int m0 = bm * 128, n0 = bn * 128;

    f32x4 acc[4][4];
#pragma unroll
    for (int i = 0; i < 4; ++i)
#pragma unroll
        for (int j = 0; j < 4; ++j) acc[i][j] = (f32x4){0.f, 0.f, 0.f, 0.f};

    for (int k0 = 0; k0 < 1024; k0 += 64) {
        __syncthreads();
#pragma unroll
        for (int it = 0; it < 4; ++it) {
            int tt = t + it * 256;
            int row = tt >> 3;
            int col = (tt & 7) * 8;
            if (AF32) {
                const float* A = (const float*)Ap;
                float4 v0 = *(const float4*)&A[(size_t)(m0 + row) * 1024 + k0 + col];
                float4 v1 = *(const float4*)&A[(size_t)(m0 + row) * 1024 + k0 + col + 4];
                bf16x8 b;
                b[0] = (short)f2bf(v0.x); b[1] = (short)f2bf(v0.y);
                b[2] = (short)f2bf(v0.z); b[3] = (short)f2bf(v0.w);
                b[4] = (short)f2bf(v1.x); b[5] = (short)f2bf(v1.y);
                b[6] = (short)f2bf(v1.z); b[7] = (short)f2bf(v1.w);
                *(bf16x8*)&As[row * 72 + col] = b;
            } else {
                const ushort_t* A = (const ushort_t*)Ap;
                *(bf16x8*)&As[row * 72 + col] =
                    *(const bf16x8*)&A[(size_t)(m0 + row) * 1024 + k0 + col];
            }
            *(bf16x8*)&Bs[row * 72 + col] =
                *(const bf16x8*)&Bt[(size_t)(n0 + row) * 1024 + k0 + col];
        }
        __syncthreads();
#pragma unroll
        for (int kt = 0; kt < 2; ++kt) {
            bf16x8 af[4], bfr[4];
#pragma unroll
            for (int mt = 0; mt < 4; ++mt)
                af[mt] = *(const bf16x8*)&As[(wr * 64 + mt * 16 + q) * 72 + kt * 32 + g * 8];
#pragma unroll
            for (int nt = 0; nt < 4; ++nt)
                bfr[nt] = *(const bf16x8*)&Bs[(wc * 64 + nt * 16 + q) * 72 + kt * 32 + g * 8];
#pragma unroll
            for (int mt = 0; mt < 4; ++mt)
#pragma unroll
                for (int nt = 0; nt < 4; ++nt)
                    acc[mt][nt] = __builtin_amdgcn_mfma_f32_16x16x32_bf16(
                        af[mt], bfr[nt], acc[mt][nt], 0, 0, 0);
        }
    }

#pragma unroll
    for (int mt = 0; mt < 4; ++mt) {
#pragma unroll
        for (int nt = 0; nt < 4; ++nt) {
#pragma unroll
            for (int r = 0; r < 4; ++r) {
                int grow = m0 + wr * 64 + mt * 16 + g * 4 + r;  // 0..8191
                int col = n0 + wc * 64 + nt * 16 + q;           // 0..1023
                float v = acc[mt][nt][r] + bias[col];
                if (OMODE == 0) {
                    int b = grow >> 11, s = grow & 2047;
                    int h = col >> 6, d = col & 63;
                    ((ushort_t*)out)[(((size_t)(b * 16 + h) * 2048 + s) * 64) + d] =
                        f2bf(v * scale);
                } else {
                    ((float*)out)[(size_t)grow * 1024 + col] = v;
                }
            }
        }
    }
}

// ---------------- flash attention, swapped-operand layout ---------------------
// Qp,Kp: [pair][s][64] bf16 (Q pre-scaled by 1/8). Vtp: [pair][d=64][s=2048].
// Out Oa: [B,S,E] bf16.
__global__ __launch_bounds__(256) void attn_kernel(const ushort_t* __restrict__ Qp,
                                                   const ushort_t* __restrict__ Kp,
                                                   const ushort_t* __restrict__ Vtp,
                                                   ushort_t* __restrict__ Oa) {
    __shared__ alignas(16) ushort_t PL[4][16 * 40];  // per-wave P tile [16 q][32 kv +pad]

    const int t = threadIdx.x, lane = t & 63, w = t >> 6;
    const int i = lane & 15, g = lane >> 4;
    // XCD-contiguous remap: 2048 blocks = 8 xcd * 256 (bijective)
    const int bid = (blockIdx.x & 7) * 256 + (blockIdx.x >> 3);
    const int pair = bid >> 5;                 // b*16 + h
    const int qbase = (bid & 31) * 64 + w * 16;

    const ushort_t* Qh = Qp + (size_t)pair * 2048 * 64;
    const ushort_t* Kh = Kp + (size_t)pair * 2048 * 64;
    const ushort_t* Vh = Vtp + (size_t)pair * 64 * 2048;
    ushort_t* pl = PL[w];

    // Q as MFMA B-operand (cols of Q^T = rows of Q): lane(i,g) -> Q[qbase+i][g*8+j]
    bf16x8 bq0 = *(const bf16x8*)&Qh[(size_t)(qbase + i) * 64 + g * 8];
    bf16x8 bq1 = *(const bf16x8*)&Qh[(size_t)(qbase + i) * 64 + 32 + g * 8];

    f32x4 o[4];
#pragma unroll
    for (int dt = 0; dt < 4; ++dt) o[dt] = (f32x4){0.f, 0.f, 0.f, 0.f};
    float m_ = -INFINITY, l_ = 0.f;

    for (int kv0 = 0; kv0 < 2048; kv0 += 32) {
        // S^T[kv, q] = K . Q^T : lane(i,g) reg r holds S[q=i][kv = 16c + g*4 + r]
        f32x4 sc[2];
        sc[0] = (f32x4){0.f, 0.f, 0.f, 0.f};
        sc[1] = (f32x4){0.f, 0.f, 0.f, 0.f};
#pragma unroll
        for (int c = 0; c < 2; ++c) {
            const ushort_t* kr = &Kh[(size_t)(kv0 + c * 16 + i) * 64];
            bf16x8 ka0 = *(const bf16x8*)&kr[g * 8];
            bf16x8 ka1 = *(const bf16x8*)&kr[32 + g * 8];
            sc[c] = __builtin_amdgcn_mfma_f32_16x16x32_bf16(ka0, bq0, sc[c], 0, 0, 0);
            sc[c] = __builtin_amdgcn_mfma_f32_16x16x32_bf16(ka1, bq1, sc[c], 0, 0, 0);
        }
        // online softmax for row q=i (8 vals per lane; reduce across g via xor16/32)
        float tmax = sc[0][0];
#pragma unroll
        for (int r = 1; r < 4; ++r) tmax = fmaxf(tmax, sc[0][r]);
#pragma unroll
        for (int r = 0; r < 4; ++r) tmax = fmaxf(tmax, sc[1][r]);
        tmax = fmaxf(tmax, __shfl_xor(tmax, 16));
        tmax = fmaxf(tmax, __shfl_xor(tmax, 32));
        float mn = fmaxf(m_, tmax);
        float corr = exp2f((m_ - mn) * LOG2E);
        float p[2][4];
        float sum = 0.f;
#pragma unroll
        for (int c = 0; c < 2; ++c)
#pragma unroll
            for (int r = 0; r < 4; ++r) {
                float e = exp2f((sc[c][r] - mn) * LOG2E);
                p[c][r] = e;
                sum += e;
            }
        sum += __shfl_xor(sum, 16);
        sum += __shfl_xor(sum, 32);
        l_ = l_ * corr + sum;
        m_ = mn;
        // pack P to LDS: pl[i*40 + kv] = P[i][kv]
#pragma unroll
        for (int c = 0; c < 2; ++c) {
            unsigned lo = (unsigned)f2bf(p[c][0]) | ((unsigned)f2bf(p[c][1]) << 16);
            unsigned hi = (unsigned)f2bf(p[c][2]) | ((unsigned)f2bf(p[c][3]) << 16);
            *(unsigned*)&pl[i * 40 + c * 16 + g * 4] = lo;
            *(unsigned*)&pl[i * 40 + c * 16 + g * 4 + 2] = hi;
        }
        // rescale O (O rows live at reg r = row g*4+r; corr lives at lane&15==row)
#pragma unroll
        for (int r = 0; r < 4; ++r) {
            float cr = __shfl(corr, g * 4 + r);
#pragma unroll
            for (int dt = 0; dt < 4; ++dt) o[dt][r] *= cr;
        }
        // PV: A = P (rows q), B = V (cols d) via Vt rows
        bf16x8 ap = *(const bf16x8*)&pl[i * 40 + g * 8];
#pragma unroll
        for (int dt = 0; dt < 4; ++dt) {
            bf16x8 bv = *(const bf16x8*)&Vh[(size_t)(dt * 16 + i) * 2048 + kv0 + g * 8];
            o[dt] = __builtin_amdgcn_mfma_f32_16x16x32_bf16(ap, bv, o[dt], 0, 0, 0);
        }
    }

    const int b = pair >> 4, h = pair & 15;
    float rl[4];
#pragma unroll
    for (int r = 0; r < 4; ++r) rl[r] = 1.0f / __shfl(l_, g * 4 + r);
#pragma unroll
    for (int dt = 0; dt < 4; ++dt) {
#pragma unroll
        for (int r = 0; r < 4; ++r) {
            int s = qbase + g * 4 + r;
            Oa[((size_t)(b * 2048 + s)) * 1024 + h * 64 + dt * 16 + i] =
                f2bf(o[dt][r] * rl[r]);
        }
    }
}

extern "C" void kernel_launch(void* const* d_in, const int* in_sizes, int n_in,
                              void* d_out, int out_size, void* d_ws, size_t ws_size,
                              hipStream_t stream) {
    const float* query = (const float*)d_in[0];
    const float* key_ = (const float*)d_in[1];
    const float* value = (const float*)d_in[2];
    const float* Wq = (const float*)d_in[3];
    const float* bq = (const float*)d_in[4];
    const float* Wk = (const float*)d_in[5];
    const float* bk = (const float*)d_in[6];
    const float* Wv = (const float*)d_in[7];
    const float* bv = (const float*)d_in[8];
    const float* Wo = (const float*)d_in[9];
    const float* bo = (const float*)d_in[10];
    float* out = (float*)d_out;

    char* ws = (char*)d_ws;
    ushort_t* Wqt = (ushort_t*)(ws + 0);
    ushort_t* Wkt = (ushort_t*)(ws + 2097152);
    ushort_t* Wvt = (ushort_t*)(ws + 4194304);
    ushort_t* Wot = (ushort_t*)(ws + 6291456);
    ushort_t* Qp = (ushort_t*)(ws + 8388608);
    ushort_t* Kp = (ushort_t*)(ws + 25165824);
    ushort_t* Vp = (ushort_t*)(ws + 41943040);
    ushort_t* Vt = (ushort_t*)(ws + 58720256);
    ushort_t* Oa = (ushort_t*)(ws + 41943040);  // aliases Vp (dead after v_transpose)
    // total ws use: 75497472 bytes

    transpose_cast<<<1024, 256, 0, stream>>>(Wq, Wqt);
    transpose_cast<<<1024, 256, 0, stream>>>(Wk, Wkt);
    transpose_cast<<<1024, 256, 0, stream>>>(Wv, Wvt);
    transpose_cast<<<1024, 256, 0, stream>>>(Wo, Wot);

    gemm_bt<1, 0><<<512, 256, 0, stream>>>((const void*)query, Wqt, bq, (void*)Qp, 0.125f);
    gemm_bt<1, 0><<<512, 256, 0, stream>>>((const void*)key_, Wkt, bk, (void*)Kp, 1.0f);
    gemm_bt<1, 0><<<512, 256, 0, stream>>>((const void*)value, Wvt, bv, (void*)Vp, 1.0f);

    v_transpose<<<2048, 256, 0, stream>>>(Vp, Vt);

    attn_kernel<<<2048, 256, 0, stream>>>(Qp, Kp, Vt, Oa);

    gemm_bt<0, 1><<<512, 256, 0, stream>>>((const void*)Oa, Wot, bo, (void*)out, 1.0f);
}

// Round 4
// 268.547 us; speedup vs baseline: 2.1864x; 2.1864x over previous
//
#include <hip/hip_runtime.h>

typedef unsigned short ushort_t;
typedef __attribute__((ext_vector_type(8))) short bf16x8;
typedef __attribute__((ext_vector_type(4))) float f32x4;
typedef __attribute__((ext_vector_type(16))) float f32x16;
typedef __attribute__((ext_vector_type(4))) int i32x4;
typedef __attribute__((ext_vector_type(2))) unsigned int u32x2;

#define QSCALE 0.1803368801111204f  /* (1/8) * log2(e): softmax in log2 domain */

__device__ inline ushort_t f2bf(float f) {
    unsigned int u = __float_as_uint(f);
    unsigned int r = (u + 0x7FFFu + ((u >> 16) & 1u)) >> 16;
    return (ushort_t)r;
}
__device__ inline unsigned pk2(float x, float y) {
    return (unsigned)f2bf(x) | ((unsigned)f2bf(y) << 16);
}
__device__ inline bf16x8 frag_from(unsigned a, unsigned b, unsigned c, unsigned d) {
    union { i32x4 i; bf16x8 v; } u;
    u.i[0] = (int)a; u.i[1] = (int)b; u.i[2] = (int)c; u.i[3] = (int)d;
    return u.v;
}

// P-fragment builder: lane (li,hi) holds P[q=li][kv_local=(r&3)+8*(r>>2)+4*hi]
// in x0..x7 (one 16-kv window). Produces B-frag: B[k=hi*8+j][col=li].
__device__ inline bf16x8 mkfrag(float x0, float x1, float x2, float x3,
                                float x4, float x5, float x6, float x7, int hi) {
    unsigned A_ = pk2(x0, x1), B_ = pk2(x2, x3), C_ = pk2(x4, x5), D_ = pk2(x6, x7);
    unsigned Ax = (unsigned)__shfl_xor((int)A_, 32);
    unsigned Bx = (unsigned)__shfl_xor((int)B_, 32);
    unsigned Cx = (unsigned)__shfl_xor((int)C_, 32);
    unsigned Dx = (unsigned)__shfl_xor((int)D_, 32);
    return frag_from(hi ? Cx : A_, hi ? Dx : B_, hi ? C_ : Ax, hi ? D_ : Bx);
}

// ------------- transpose + cast all 4 weights: W[K,N] f32 -> Wt[N,K] bf16 ----
__global__ __launch_bounds__(256) void transpose_cast4(
    const float* __restrict__ W0, const float* __restrict__ W1,
    const float* __restrict__ W2, const float* __restrict__ W3,
    ushort_t* __restrict__ T0, ushort_t* __restrict__ T1,
    ushort_t* __restrict__ T2, ushort_t* __restrict__ T3) {
    __shared__ float tile[32][33];
    const int which = blockIdx.x >> 10;
    const float* W = which == 0 ? W0 : which == 1 ? W1 : which == 2 ? W2 : W3;
    ushort_t* Wt = which == 0 ? T0 : which == 1 ? T1 : which == 2 ? T2 : T3;
    const int bidx = blockIdx.x & 1023;
    const int bx = bidx & 31, by = bidx >> 5;
    const int n0 = bx * 32, k0 = by * 32;
    const int tx = threadIdx.x & 31, ty = threadIdx.x >> 5;
#pragma unroll
    for (int i = 0; i < 4; ++i) {
        int r = ty + i * 8;
        tile[r][tx] = W[(k0 + r) * 1024 + n0 + tx];
    }
    __syncthreads();
#pragma unroll
    for (int i = 0; i < 4; ++i) {
        int r = ty + i * 8;
        Wt[(n0 + r) * 1024 + k0 + tx] = f2bf(tile[tx][r]);
    }
}

// ---------------- V transpose: Vp[pair][s][d=64] -> Vt[pair][d][s=2048] bf16 --
__global__ __launch_bounds__(256) void v_transpose(const ushort_t* __restrict__ Vp,
                                                   ushort_t* __restrict__ Vt) {
    __shared__ alignas(16) ushort_t tile[64][72];
    const int bid = blockIdx.x;
    const int pair = bid >> 5, st0 = (bid & 31) * 64;
    const ushort_t* src = Vp + (size_t)pair * 2048 * 64;
    ushort_t* dst = Vt + (size_t)pair * 64 * 2048;
    const int t = threadIdx.x;
    const int sl = t >> 2, d0 = (t & 3) * 16;
    *(bf16x8*)&tile[sl][d0] = *(const bf16x8*)&src[(size_t)(st0 + sl) * 64 + d0];
    *(bf16x8*)&tile[sl][d0 + 8] = *(const bf16x8*)&src[(size_t)(st0 + sl) * 64 + d0 + 8];
    __syncthreads();
    const int dl = t >> 2, s0 = (t & 3) * 16;
    bf16x8 a, b;
#pragma unroll
    for (int j = 0; j < 8; ++j) {
        a[j] = (short)tile[s0 + j][dl];
        b[j] = (short)tile[s0 + 8 + j][dl];
    }
    *(bf16x8*)&dst[(size_t)dl * 2048 + st0 + s0] = a;
    *(bf16x8*)&dst[(size_t)dl * 2048 + st0 + s0 + 8] = b;
}

// ---------------- GEMM: C[M=8192, N=1024] = A[M,1024] @ Wt[N,1024]^T + bias ---
template <int AF32, int OMODE>
__global__ __launch_bounds__(256) void gemm_bt(const void* __restrict__ Ap,
                                               const ushort_t* __restrict__ Bt,
                                               const float* __restrict__ bias,
                                               void* __restrict__ out, float scale) {
    __shared__ alignas(16) ushort_t As[128 * 72];
    __shared__ alignas(16) ushort_t Bs[128 * 72];
    const int t = threadIdx.x;
    const int lane = t & 63, w = t >> 6;
    const int q = lane & 15, g = lane >> 4;
    const int wr = w >> 1, wc = w & 1;
    const int bm = blockIdx.x & 63, bn = blockIdx.x >> 6;
    const int m0 = bm * 128, n0 = bn * 128;

    f32x4 acc[4][4];
#pragma unroll
    for (int i = 0; i < 4; ++i)
#pragma unroll
        for (int j = 0; j < 4; ++j) acc[i][j] = (f32x4){0.f, 0.f, 0.f, 0.f};

    for (int k0 = 0; k0 < 1024; k0 += 64) {
        __syncthreads();
#pragma unroll
        for (int it = 0; it < 4; ++it) {
            int tt = t + it * 256;
            int row = tt >> 3;
            int col = (tt & 7) * 8;
            if (AF32) {
                const float* A = (const float*)Ap;
                float4 v0 = *(const float4*)&A[(size_t)(m0 + row) * 1024 + k0 + col];
                float4 v1 = *(const float4*)&A[(size_t)(m0 + row) * 1024 + k0 + col + 4];
                bf16x8 b;
                b[0] = (short)f2bf(v0.x); b[1] = (short)f2bf(v0.y);
                b[2] = (short)f2bf(v0.z); b[3] = (short)f2bf(v0.w);
                b[4] = (short)f2bf(v1.x); b[5] = (short)f2bf(v1.y);
                b[6] = (short)f2bf(v1.z); b[7] = (short)f2bf(v1.w);
                *(bf16x8*)&As[row * 72 + col] = b;
            } else {
                const ushort_t* A = (const ushort_t*)Ap;
                *(bf16x8*)&As[row * 72 + col] =
                    *(const bf16x8*)&A[(size_t)(m0 + row) * 1024 + k0 + col];
            }
            *(bf16x8*)&Bs[row * 72 + col] =
                *(const bf16x8*)&Bt[(size_t)(n0 + row) * 1024 + k0 + col];
        }
        __syncthreads();
#pragma unroll
        for (int kt = 0; kt < 2; ++kt) {
            bf16x8 af[4], bfr[4];
#pragma unroll
            for (int mt = 0; mt < 4; ++mt)
                af[mt] = *(const bf16x8*)&As[(wr * 64 + mt * 16 + q) * 72 + kt * 32 + g * 8];
#pragma unroll
            for (int nt = 0; nt < 4; ++nt)
                bfr[nt] = *(const bf16x8*)&Bs[(wc * 64 + nt * 16 + q) * 72 + kt * 32 + g * 8];
#pragma unroll
            for (int mt = 0; mt < 4; ++mt)
#pragma unroll
                for (int nt = 0; nt < 4; ++nt)
                    acc[mt][nt] = __builtin_amdgcn_mfma_f32_16x16x32_bf16(
                        af[mt], bfr[nt], acc[mt][nt], 0, 0, 0);
        }
    }

#pragma unroll
    for (int mt = 0; mt < 4; ++mt) {
#pragma unroll
        for (int nt = 0; nt < 4; ++nt) {
#pragma unroll
            for (int r = 0; r < 4; ++r) {
                int grow = m0 + wr * 64 + mt * 16 + g * 4 + r;
                int col = n0 + wc * 64 + nt * 16 + q;
                float v = acc[mt][nt][r] + bias[col];
                if (OMODE == 0) {
                    int b = grow >> 11, s = grow & 2047;
                    int h = col >> 6, d = col & 63;
                    ((ushort_t*)out)[(((size_t)(b * 16 + h) * 2048 + s) * 64) + d] =
                        f2bf(v * scale);
                } else {
                    ((float*)out)[(size_t)grow * 1024 + col] = v;
                }
            }
        }
    }
}

// ---------------- flash attention, 32x32 swapped-operand, reg-staged K/V -----
// Qp,Kp: [pair][s][64] bf16 (Q pre-scaled by QSCALE). Vtp: [pair][d=64][s=2048].
// Per block: 4 waves x 32 q rows = 128 q. Grid: 64 pairs * 16 = 1024 blocks.
__global__ __launch_bounds__(256, 2) void attn_kernel(const ushort_t* __restrict__ Qp,
                                                      const ushort_t* __restrict__ Kp,
                                                      const ushort_t* __restrict__ Vtp,
                                                      ushort_t* __restrict__ Oa) {
    __shared__ alignas(16) ushort_t Ks[4096];  // [64 kv][64 d], rows XOR-swizzled
    __shared__ alignas(16) ushort_t Vs[4096];  // [64 d][64 kv], rows XOR-swizzled

    const int t = threadIdx.x, lane = t & 63, w = t >> 6;
    const int li = lane & 31, hi = lane >> 5;
    // XCD-contiguous remap: 1024 = 8 xcd * 128 (bijective); pair = bid>>4
    const int bid = (blockIdx.x & 7) * 128 + (blockIdx.x >> 3);
    const int pair = bid >> 4;
    const int qbase = (bid & 15) * 128 + w * 32;

    const ushort_t* Qh = Qp + (size_t)pair * 2048 * 64;
    const ushort_t* Kh = Kp + (size_t)pair * 2048 * 64;
    const ushort_t* Vh = Vtp + (size_t)pair * 64 * 2048;

    // Q B-frags: B[k][col=li] = Q[qbase+li][k], k = ks*16 + hi*8 + j
    bf16x8 qf[4];
#pragma unroll
    for (int ks = 0; ks < 4; ++ks)
        qf[ks] = *(const bf16x8*)&Qh[(size_t)(qbase + li) * 64 + ks * 16 + hi * 8];

    f32x16 o0 = {0.f,0.f,0.f,0.f,0.f,0.f,0.f,0.f,0.f,0.f,0.f,0.f,0.f,0.f,0.f,0.f};
    f32x16 o1 = {0.f,0.f,0.f,0.f,0.f,0.f,0.f,0.f,0.f,0.f,0.f,0.f,0.f,0.f,0.f,0.f};
    float m_ = -1e30f, l_ = 0.f;

    // staging geometry: thread t loads 16B at (row r8, slot t&7), writes LDS at
    // swizzled slot (t&7)^(r8&7). Read side applies the same XOR -> consistent.
    const int r8 = t >> 3;                 // 0..31
    const int lcol = (t & 7) * 16;         // source byte col
    const int swcol = lcol ^ ((r8 & 7) << 4);
    const char* Kc = (const char*)Kh;
    const char* Vc = (const char*)Vh;
    char* KsB = (char*)Ks;
    char* VsB = (char*)Vs;

    i32x4 gk0 = *(const i32x4*)(Kc + (size_t)r8 * 128 + lcol);
    i32x4 gk1 = *(const i32x4*)(Kc + (size_t)(32 + r8) * 128 + lcol);
    i32x4 gv0 = *(const i32x4*)(Vc + (size_t)r8 * 4096 + lcol);
    i32x4 gv1 = *(const i32x4*)(Vc + (size_t)(32 + r8) * 4096 + lcol);

    for (int it = 0; it < 32; ++it) {
        __syncthreads();  // all waves done reading previous tile
        *(i32x4*)(KsB + r8 * 128 + swcol) = gk0;
        *(i32x4*)(KsB + (32 + r8) * 128 + swcol) = gk1;
        *(i32x4*)(VsB + r8 * 128 + swcol) = gv0;
        *(i32x4*)(VsB + (32 + r8) * 128 + swcol) = gv1;
        if (it < 31) {  // issue next-tile loads early; latency hides under compute
            const int kn = (it + 1) * 64;
            gk0 = *(const i32x4*)(Kc + (size_t)(kn + r8) * 128 + lcol);
            gk1 = *(const i32x4*)(Kc + (size_t)(kn + 32 + r8) * 128 + lcol);
            gv0 = *(const i32x4*)(Vc + (size_t)r8 * 4096 + kn * 2 + lcol);
            gv1 = *(const i32x4*)(Vc + (size_t)(32 + r8) * 4096 + kn * 2 + lcol);
        }
        __syncthreads();  // tile staged

        const int sw = (li & 7) << 4;

        // --- QK^T: S^T[kv][q], two 32-kv halves ---
        f32x16 s0 = {0.f,0.f,0.f,0.f,0.f,0.f,0.f,0.f,0.f,0.f,0.f,0.f,0.f,0.f,0.f,0.f};
        f32x16 s1 = {0.f,0.f,0.f,0.f,0.f,0.f,0.f,0.f,0.f,0.f,0.f,0.f,0.f,0.f,0.f,0.f};
#pragma unroll
        for (int ks = 0; ks < 4; ++ks) {
            const int b = ks * 32 + hi * 16;
            bf16x8 k0 = *(const bf16x8*)(KsB + li * 128 + (b ^ sw));
            bf16x8 k1 = *(const bf16x8*)(KsB + (32 + li) * 128 + (b ^ sw));
            s0 = __builtin_amdgcn_mfma_f32_32x32x16_bf16(k0, qf[ks], s0, 0, 0, 0);
            s1 = __builtin_amdgcn_mfma_f32_32x32x16_bf16(k1, qf[ks], s1, 0, 0, 0);
        }

        // --- online softmax (log2 domain), lane-local rows ---
        float tm = s0[0];
#pragma unroll
        for (int r = 1; r < 16; ++r) tm = fmaxf(tm, s0[r]);
#pragma unroll
        for (int r = 0; r < 16; ++r) tm = fmaxf(tm, s1[r]);
        tm = fmaxf(tm, __shfl_xor(tm, 32));
        if (__any(tm > m_ + 8.f)) {  // defer-max (T13)
            float mn = fmaxf(m_, tm);
            float corr = exp2f(m_ - mn);
#pragma unroll
            for (int r = 0; r < 16; ++r) { o0[r] *= corr; o1[r] *= corr; }
            l_ *= corr;
            m_ = mn;
        }
        float sum = 0.f;
#pragma unroll
        for (int r = 0; r < 16; ++r) {
            s0[r] = exp2f(s0[r] - m_);
            sum += s0[r];
        }
#pragma unroll
        for (int r = 0; r < 16; ++r) {
            s1[r] = exp2f(s1[r] - m_);
            sum += s1[r];
        }
        sum += __shfl_xor(sum, 32);
        l_ += sum;

        // --- pack P -> 4 B-frags (pk2 + shfl_xor + select; safe primitives) ---
        bf16x8 pf[4];
        pf[0] = mkfrag(s0[0], s0[1], s0[2], s0[3], s0[4], s0[5], s0[6], s0[7], hi);
        pf[1] = mkfrag(s0[8], s0[9], s0[10], s0[11], s0[12], s0[13], s0[14], s0[15], hi);
        pf[2] = mkfrag(s1[0], s1[1], s1[2], s1[3], s1[4], s1[5], s1[6], s1[7], hi);
        pf[3] = mkfrag(s1[8], s1[9], s1[10], s1[11], s1[12], s1[13], s1[14], s1[15], hi);

        // --- PV: O^T[d][q] += V^T . P^T ---
#pragma unroll
        for (int ks = 0; ks < 4; ++ks) {
            const int b = ks * 32 + hi * 16;
            bf16x8 v0 = *(const bf16x8*)(VsB + li * 128 + (b ^ sw));
            bf16x8 v1 = *(const bf16x8*)(VsB + (32 + li) * 128 + (b ^ sw));
            o0 = __builtin_amdgcn_mfma_f32_32x32x16_bf16(v0, pf[ks], o0, 0, 0, 0);
            o1 = __builtin_amdgcn_mfma_f32_32x32x16_bf16(v1, pf[ks], o1, 0, 0, 0);
        }
    }

    // --- epilogue: lane pair (li,hi) owns q=qbase+li; o_dt[r] = O^T[d][q],
    //     d = (r&3) + 8*(r>>2) + 4*hi + 32*dt ---
    const float rl = 1.0f / l_;
    const int b = pair >> 4, hh = pair & 15;
    const int s = qbase + li;
    const size_t rowbase = ((size_t)(b * 2048 + s)) * 1024 + hh * 64;
#pragma unroll
    for (int dt = 0; dt < 2; ++dt) {
#pragma unroll
        for (int rq = 0; rq < 4; ++rq) {
            float v0 = (dt ? o1[rq * 4 + 0] : o0[rq * 4 + 0]) * rl;
            float v1 = (dt ? o1[rq * 4 + 1] : o0[rq * 4 + 1]) * rl;
            float v2 = (dt ? o1[rq * 4 + 2] : o0[rq * 4 + 2]) * rl;
            float v3 = (dt ? o1[rq * 4 + 3] : o0[rq * 4 + 3]) * rl;
            u32x2 uv;
            uv[0] = (unsigned)f2bf(v0) | ((unsigned)f2bf(v1) << 16);
            uv[1] = (unsigned)f2bf(v2) | ((unsigned)f2bf(v3) << 16);
            *(u32x2*)&Oa[rowbase + dt * 32 + rq * 8 + hi * 4] = uv;
        }
    }
}

extern "C" void kernel_launch(void* const* d_in, const int* in_sizes, int n_in,
                              void* d_out, int out_size, void* d_ws, size_t ws_size,
                              hipStream_t stream) {
    const float* query = (const float*)d_in[0];
    const float* key_ = (const float*)d_in[1];
    const float* value = (const float*)d_in[2];
    const float* Wq = (const float*)d_in[3];
    const float* bq = (const float*)d_in[4];
    const float* Wk = (const float*)d_in[5];
    const float* bk = (const float*)d_in[6];
    const float* Wv = (const float*)d_in[7];
    const float* bv = (const float*)d_in[8];
    const float* Wo = (const float*)d_in[9];
    const float* bo = (const float*)d_in[10];
    float* out = (float*)d_out;

    char* ws = (char*)d_ws;
    ushort_t* Wqt = (ushort_t*)(ws + 0);
    ushort_t* Wkt = (ushort_t*)(ws + 2097152);
    ushort_t* Wvt = (ushort_t*)(ws + 4194304);
    ushort_t* Wot = (ushort_t*)(ws + 6291456);
    ushort_t* Qp = (ushort_t*)(ws + 8388608);
    ushort_t* Kp = (ushort_t*)(ws + 25165824);
    ushort_t* Vp = (ushort_t*)(ws + 41943040);
    ushort_t* Vt = (ushort_t*)(ws + 58720256);
    ushort_t* Oa = (ushort_t*)(ws + 41943040);  // aliases Vp (dead after v_transpose)

    transpose_cast4<<<4096, 256, 0, stream>>>(Wq, Wk, Wv, Wo, Wqt, Wkt, Wvt, Wot);

    gemm_bt<1, 0><<<512, 256, 0, stream>>>((const void*)query, Wqt, bq, (void*)Qp, QSCALE);
    gemm_bt<1, 0><<<512, 256, 0, stream>>>((const void*)key_, Wkt, bk, (void*)Kp, 1.0f);
    gemm_bt<1, 0><<<512, 256, 0, stream>>>((const void*)value, Wvt, bv, (void*)Vp, 1.0f);

    v_transpose<<<2048, 256, 0, stream>>>(Vp, Vt);

    attn_kernel<<<1024, 256, 0, stream>>>(Qp, Kp, Vt, Oa);

    gemm_bt<0, 1><<<512, 256, 0, stream>>>((const void*)Oa, Wot, bo, (void*)out, 1.0f);
}